// Round 5
// baseline (6907.378 us; speedup 1.0000x reference)
//
#include <hip/hip_runtime.h>

// ---------------------------------------------------------------------------
// R5: fused one-launch-per-step encoder with split-bf16 MFMA.
//  enc_step_fused (grid 256 = 8mt x 32nt, 256 thr = 4 waves):
//   phase 1 (t>=1): block redundantly updates its OWN 32 rows from z_{t-1}
//     (softmax row-local). h -> LDS as A-fragments (hi/lo bf16). c parity-
//     buffered, written by nt==0 only. t==256: nt==0 writes henc.
//   phase 2 (t<256): z_t[32rows x 64cols] = [x_t | h] @ [W;U] via
//     mfma_f32_32x32x16_bf16, 3 products (hh+hl+lh). B-fragments pre-packed
//     in global (bfrag_prep). 4 waves = 2 col-tiles x 2-way k-split + LDS
//     partial reduction. z parity-buffered.
// Decoder/dense: R3/R4 verified kernels, unchanged.
// ---------------------------------------------------------------------------

typedef __attribute__((ext_vector_type(8)))  short bf16x8;
typedef __attribute__((ext_vector_type(4)))  short short4v;
typedef __attribute__((ext_vector_type(16))) float f32x16;

#define MFMA(a, b, c) __builtin_amdgcn_mfma_f32_32x32x16_bf16((a), (b), (c), 0, 0, 0)

// ws layout (float offsets). [0, 8388608) = hseq (dec) ALIASED with bh/bl (enc).
#define OFS_ZENC  8388608u    // [2][256][2048]  (decoder reuses as zdec)
#define OFS_CENC  9437184u    // [2][256][512]   (decoder reuses as cdec)
#define OFS_HENC  9699328u    // [256][512]
#define OFS_XWD   9830400u    // [256][2048]
#define WS_FLOATS 10354688u   // 41.4 MB

__device__ __forceinline__ float frcp(float x) { return __builtin_amdgcn_rcpf(x); }
__device__ __forceinline__ float sigm(float x) { return frcp(1.0f + __expf(-x)); }
__device__ __forceinline__ float tanh1(float x) {
    return 2.0f * frcp(1.0f + __expf(-2.0f * x)) - 1.0f;
}
__device__ __forceinline__ float4 ld4(const float* p) { return *(const float4*)p; }
__device__ __forceinline__ void st4(float* p, float4 v) { *(float4*)p = v; }
__device__ __forceinline__ float4 add4(float4 a, float4 b) {
    return float4{a.x + b.x, a.y + b.y, a.z + b.z, a.w + b.w};
}
__device__ __forceinline__ float4 exp4(float4 a) {
    return float4{__expf(a.x), __expf(a.y), __expf(a.z), __expf(a.w)};
}
__device__ __forceinline__ float hsum4(float4 a) { return (a.x + a.y) + (a.z + a.w); }

__device__ __forceinline__ short f2bf(float f) {      // fp32 -> bf16 RNE
    unsigned u = __float_as_uint(f);
    u = u + 0x7FFFu + ((u >> 16) & 1u);
    return (short)(u >> 16);
}
__device__ __forceinline__ float bf2f(short s) {
    return __uint_as_float(((unsigned)(unsigned short)s) << 16);
}

// ---------------------------------------------------------------------------
// Pack W(64x2048),U(512x2048) into B-fragment order (R4-verified):
// lane l holds B[k = ks*16 + (l>>5)*8 + j][col = ct*32 + (l&31)], j=0..7.
// ---------------------------------------------------------------------------
__global__ __launch_bounds__(64) void bfrag_prep(
    const float* __restrict__ W, const float* __restrict__ U,
    short* __restrict__ bh, short* __restrict__ bl)
{
    const int ks = blockIdx.x;          // 0..35
    const int ct = blockIdx.y;          // 0..63
    const int l  = threadIdx.x;         // 0..63
    const int col = ct * 32 + (l & 31);
    const int kbase = ks * 16 + (l >> 5) * 8;
    bf16x8 h8, l8;
    #pragma unroll
    for (int j = 0; j < 8; ++j) {
        const int k = kbase + j;
        const float v = (k < 64) ? W[(size_t)k * 2048 + col]
                                 : U[(size_t)(k - 64) * 2048 + col];
        const short hi = f2bf(v);
        h8[j] = hi;
        l8[j] = f2bf(v - bf2f(hi));
    }
    const size_t off = ((size_t)(ct * 36 + ks) * 64 + l) * 8;
    *(bf16x8*)(bh + off) = h8;
    *(bf16x8*)(bl + off) = l8;
}

// ---------------------------------------------------------------------------
// Fused encoder step. Dynamic LDS: afh[16384]s, afl[16384]s, red[512]f4.
// ---------------------------------------------------------------------------
__global__ __launch_bounds__(256) void enc_step_fused(
    const float* __restrict__ x,     // [256][256][64]
    const short* __restrict__ bh, const short* __restrict__ bl,
    const float* __restrict__ bias,  // [2048]
    float* __restrict__ zenc,        // [2][256][2048]
    float* __restrict__ cenc,        // [2][256][512]
    float* __restrict__ henc,        // [256][512]
    int t)
{
    extern __shared__ short lds_s[];
    short* afh = lds_s;                        // 32 KB
    short* afl = lds_s + 16384;                // 32 KB
    float4* redv = (float4*)(lds_s + 32768);   // 8 KB

    const int bid = blockIdx.x;
    const int nt = bid & 31, mt = bid >> 5;
    const int tid = threadIdx.x;

    // ---- phase 1: update own 32 rows from z_{t-1} (redundant across nt) ----
    if (t >= 1) {
        const int r = tid >> 3, ug = tid & 7;      // 32 rows x 8 thr/row
        const int grow = mt * 32 + r;
        const float* zr = zenc + (size_t)((t - 1) & 1) * 524288 + (size_t)grow * 2048;
        const float* cop = cenc + (size_t)(t & 1) * 131072 + (size_t)grow * 512;
        float*       cnp = cenc + (size_t)((t + 1) & 1) * 131072 + (size_t)grow * 512;

        float4 ereg[16];
        float sg = 0.f;
        #pragma unroll
        for (int m = 0; m < 16; ++m) {
            const int idx = m * 32 + ug * 4;
            float4 g = add4(ld4(zr + 1024 + idx), ld4(bias + 1024 + idx));
            g = exp4(g);
            ereg[m] = g;
            sg += hsum4(g);
        }
        sg += __shfl_xor(sg, 1); sg += __shfl_xor(sg, 2); sg += __shfl_xor(sg, 4);
        const float ginv = frcp(sg);

        float sc = 0.f;
        #pragma unroll
        for (int m = 0; m < 16; ++m) {
            const int idx = m * 32 + ug * 4;
            const float4 zi = add4(ld4(zr + idx), ld4(bias + idx));
            const float4 zf = add4(ld4(zr + 512 + idx), ld4(bias + 512 + idx));
            float4 co{0.f, 0.f, 0.f, 0.f};
            if (t >= 2) co = ld4(cop + idx);
            float4 cv;
            cv.x = sigm(zf.x) * co.x + sigm(zi.x) * (ereg[m].x * ginv);
            cv.y = sigm(zf.y) * co.y + sigm(zi.y) * (ereg[m].y * ginv);
            cv.z = sigm(zf.z) * co.z + sigm(zi.z) * (ereg[m].z * ginv);
            cv.w = sigm(zf.w) * co.w + sigm(zi.w) * (ereg[m].w * ginv);
            if (nt == 0) st4(cnp + idx, cv);
            const float4 ec = exp4(cv);
            ereg[m] = ec;
            sc += hsum4(ec);
        }
        sc += __shfl_xor(sc, 1); sc += __shfl_xor(sc, 2); sc += __shfl_xor(sc, 4);
        const float cinv = frcp(sc);

        const int lane_slot = ((ug >> 1) & 1) * 32 + r;
        const int j0 = (ug & 1) * 4;
        #pragma unroll
        for (int m = 0; m < 16; ++m) {
            const int idx = m * 32 + ug * 4;
            const float4 zo = add4(ld4(zr + 1536 + idx), ld4(bias + 1536 + idx));
            float4 h;
            h.x = sigm(zo.x) * ereg[m].x * cinv;
            h.y = sigm(zo.y) * ereg[m].y * cinv;
            h.z = sigm(zo.z) * ereg[m].z * cinv;
            h.w = sigm(zo.w) * ereg[m].w * cinv;
            // LDS A-frag: unit u = idx + (0..3); ks=u>>4, lane=((u>>3)&1)*32+r, j=u&7
            const int ks = 2 * m + (ug >> 2);
            const int aoff = (ks * 64 + lane_slot) * 8 + j0;
            short4v hv, lv;
            hv.x = f2bf(h.x); lv.x = f2bf(h.x - bf2f(hv.x));
            hv.y = f2bf(h.y); lv.y = f2bf(h.y - bf2f(hv.y));
            hv.z = f2bf(h.z); lv.z = f2bf(h.z - bf2f(hv.z));
            hv.w = f2bf(h.w); lv.w = f2bf(h.w - bf2f(hv.w));
            *(short4v*)(afh + aoff) = hv;
            *(short4v*)(afl + aoff) = lv;
            if (t == 256 && nt == 0) st4(henc + (size_t)grow * 512 + idx, h);
        }
    }
    __syncthreads();

    // ---- phase 2: z_t tile via MFMA (2 ct x 2-way k-split) ----
    if (t < 256) {
        const int w = tid >> 6, l = tid & 63;
        const int ctl = w & 1, kh = w >> 1;
        const int ct = nt * 2 + ctl;

        f32x16 acc;
        #pragma unroll
        for (int i = 0; i < 16; ++i) acc[i] = 0.f;

        if (kh == 0) {
            // x slabs 0..3 (A built on the fly, R4-verified mapping)
            const int row = mt * 32 + (l & 31);
            const float* xp = x + ((size_t)row * 256 + t) * 64 + (l >> 5) * 8;
            #pragma unroll
            for (int ks = 0; ks < 4; ++ks) {
                float xv[8];
                const float4 xa = ld4(xp + ks * 16);
                const float4 xb = ld4(xp + ks * 16 + 4);
                xv[0] = xa.x; xv[1] = xa.y; xv[2] = xa.z; xv[3] = xa.w;
                xv[4] = xb.x; xv[5] = xb.y; xv[6] = xb.z; xv[7] = xb.w;
                bf16x8 ah, al;
                #pragma unroll
                for (int j = 0; j < 8; ++j) {
                    const short hi = f2bf(xv[j]);
                    ah[j] = hi;
                    al[j] = f2bf(xv[j] - bf2f(hi));
                }
                const size_t boff = ((size_t)(ct * 36 + ks) * 64 + l) * 8;
                const bf16x8 bhv = *(const bf16x8*)(bh + boff);
                const bf16x8 blv = *(const bf16x8*)(bl + boff);
                acc = MFMA(ah, bhv, acc);
                acc = MFMA(ah, blv, acc);
                acc = MFMA(al, bhv, acc);
            }
            if (t >= 1) {
                for (int ksh = 0; ksh < 14; ++ksh) {
                    const bf16x8 ah = *(const bf16x8*)(afh + (ksh * 64 + l) * 8);
                    const bf16x8 al = *(const bf16x8*)(afl + (ksh * 64 + l) * 8);
                    const size_t boff = ((size_t)(ct * 36 + 4 + ksh) * 64 + l) * 8;
                    const bf16x8 bhv = *(const bf16x8*)(bh + boff);
                    const bf16x8 blv = *(const bf16x8*)(bl + boff);
                    acc = MFMA(ah, bhv, acc);
                    acc = MFMA(ah, blv, acc);
                    acc = MFMA(al, bhv, acc);
                }
            }
        } else if (t >= 1) {
            for (int ksh = 14; ksh < 32; ++ksh) {
                const bf16x8 ah = *(const bf16x8*)(afh + (ksh * 64 + l) * 8);
                const bf16x8 al = *(const bf16x8*)(afl + (ksh * 64 + l) * 8);
                const size_t boff = ((size_t)(ct * 36 + 4 + ksh) * 64 + l) * 8;
                const bf16x8 bhv = *(const bf16x8*)(bh + boff);
                const bf16x8 blv = *(const bf16x8*)(bl + boff);
                acc = MFMA(ah, bhv, acc);
                acc = MFMA(ah, blv, acc);
                acc = MFMA(al, bhv, acc);
            }
        }

        if (kh == 1) {
            #pragma unroll
            for (int q = 0; q < 4; ++q)
                redv[(ctl * 64 + l) * 4 + q] =
                    float4{acc[4 * q], acc[4 * q + 1], acc[4 * q + 2], acc[4 * q + 3]};
        }
        __syncthreads();
        if (kh == 0) {
            #pragma unroll
            for (int q = 0; q < 4; ++q) {
                const float4 pv = redv[(ctl * 64 + l) * 4 + q];
                acc[4 * q] += pv.x; acc[4 * q + 1] += pv.y;
                acc[4 * q + 2] += pv.z; acc[4 * q + 3] += pv.w;
            }
            // C/D layout (R4-verified): col=l&31, row=(i&3)+8*(i>>2)+4*(l>>5)
            float* zp = zenc + (size_t)(t & 1) * 524288;
            const int colg = ct * 32 + (l & 31);
            #pragma unroll
            for (int i = 0; i < 16; ++i) {
                const int m2 = (i & 3) + 8 * (i >> 2) + 4 * (l >> 5);
                zp[(size_t)(mt * 32 + m2) * 2048 + colg] = acc[i];
            }
        }
    }
}

// ---------------------------------------------------------------------------
// Decoder (R3/R4-verified): fused step kernel, fp32 VALU.
// ---------------------------------------------------------------------------
__global__ __launch_bounds__(256) void dec_step(
    const float* __restrict__ Uf, const float* __restrict__ Ub,
    const float* __restrict__ xwd, float* __restrict__ zdec,
    float* __restrict__ cdec, float* __restrict__ hseq, int s)
{
    __shared__ float Asd[256 * 33];
    __shared__ float Bsd[2][2048];
    const int bid = blockIdx.x;
    const int nt = bid & 31, mt = bid >> 5;
    const int dir = nt >> 4;
    const int tid = threadIdx.x;

    {
        const int r = tid >> 3, ug = tid & 7;
        const int grow = mt * 32 + r;
        const float* zr = zdec + (size_t)((s - 1) & 1) * 524288 + (size_t)grow * 2048 + dir * 1024;
        const float* xp = xwd + (size_t)grow * 2048 + dir * 1024;
        const float* cp = cdec + (size_t)(s & 1) * 131072 + dir * 65536 + (size_t)grow * 256;
        float*       cn = cdec + (size_t)((s + 1) & 1) * 131072 + dir * 65536 + (size_t)grow * 256;
        const int tt = dir ? (64 - s) : (s - 1);
        #pragma unroll
        for (int m = 0; m < 8; ++m) {
            const int idx = m * 32 + ug * 4;
            float4 zi = ld4(xp + idx);
            float4 zf = ld4(xp + 256 + idx);
            float4 zg = ld4(xp + 512 + idx);
            float4 zo = ld4(xp + 768 + idx);
            float4 cv0{0.f, 0.f, 0.f, 0.f};
            if (s > 1) {
                zi = add4(zi, ld4(zr + idx));
                zf = add4(zf, ld4(zr + 256 + idx));
                zg = add4(zg, ld4(zr + 512 + idx));
                zo = add4(zo, ld4(zr + 768 + idx));
                cv0 = ld4(cp + idx);
            }
            float4 cv, h;
            cv.x = sigm(zf.x) * cv0.x + sigm(zi.x) * tanh1(zg.x);
            cv.y = sigm(zf.y) * cv0.y + sigm(zi.y) * tanh1(zg.y);
            cv.z = sigm(zf.z) * cv0.z + sigm(zi.z) * tanh1(zg.z);
            cv.w = sigm(zf.w) * cv0.w + sigm(zi.w) * tanh1(zg.w);
            st4(cn + idx, cv);
            h.x = sigm(zo.x) * tanh1(cv.x); h.y = sigm(zo.y) * tanh1(cv.y);
            h.z = sigm(zo.z) * tanh1(cv.z); h.w = sigm(zo.w) * tanh1(cv.w);
            Asd[(idx + 0) * 33 + r] = h.x; Asd[(idx + 1) * 33 + r] = h.y;
            Asd[(idx + 2) * 33 + r] = h.z; Asd[(idx + 3) * 33 + r] = h.w;
            if ((nt & 15) == 0)
                st4(hseq + ((size_t)grow * 64 + tt) * 512 + dir * 256 + idx, h);
        }
    }
    __syncthreads();

    if (s < 64) {
        const int tr = tid >> 4, tc = tid & 15;
        const int brow = tid >> 3, bcg = (tid & 7) * 8;
        const int cl = (nt & 15) * 64;
        const float* Ud = dir ? Ub : Uf;
        float4 a0{0.f, 0.f, 0.f, 0.f}, a1{0.f, 0.f, 0.f, 0.f};

        const float* bp0 = Ud + (size_t)brow * 1024 + cl + bcg;
        float4 pb0 = ld4(bp0), pb1 = ld4(bp0 + 4);

        for (int ch = 0; ch < 8; ++ch) {
            float* bs = Bsd[ch & 1];
            st4(bs + brow * 64 + bcg, pb0);
            st4(bs + brow * 64 + bcg + 4, pb1);
            __syncthreads();
            if (ch + 1 < 8) {
                const int k = (ch + 1) * 32 + brow;
                const float* bp = Ud + (size_t)k * 1024 + cl + bcg;
                pb0 = ld4(bp); pb1 = ld4(bp + 4);
            }
            const int kb = ch * 32;
            #pragma unroll
            for (int kk = 0; kk < 32; ++kk) {
                const float av0 = Asd[(kb + kk) * 33 + tr];
                const float av1 = Asd[(kb + kk) * 33 + tr + 16];
                const float4 b = ld4(bs + kk * 64 + tc * 4);
                a0.x = fmaf(av0, b.x, a0.x); a0.y = fmaf(av0, b.y, a0.y);
                a0.z = fmaf(av0, b.z, a0.z); a0.w = fmaf(av0, b.w, a0.w);
                a1.x = fmaf(av1, b.x, a1.x); a1.y = fmaf(av1, b.y, a1.y);
                a1.z = fmaf(av1, b.z, a1.z); a1.w = fmaf(av1, b.w, a1.w);
            }
            __syncthreads();
        }
        float* zo = zdec + (size_t)(s & 1) * 524288 + (size_t)(mt * 32) * 2048 + (size_t)nt * 64;
        st4(zo + tr * 2048 + tc * 4, a0);
        st4(zo + (tr + 16) * 2048 + tc * 4, a1);
    }
}

__global__ __launch_bounds__(128) void dec_proj(
    const float* __restrict__ A, const float* __restrict__ Bf,
    const float* __restrict__ Bb, const float* __restrict__ bf,
    const float* __restrict__ bb, float* __restrict__ xwd)
{
    const int n0 = blockIdx.x * 64;
    const int m0 = blockIdx.y * 32;
    __shared__ __align__(16) float As[16][36];
    __shared__ __align__(16) float Bs[16][68];
    const int tid = threadIdx.x;
    const int am = tid & 31, akq = tid >> 5;
    const int bc4 = tid & 15, bkr = tid >> 4;
    const int cr = tid >> 4, cc = tid & 15;

    float acc[4][4] = {};
    const float* bp = (n0 < 1024) ? Bf : Bb;
    const float* bia = (n0 < 1024) ? bf : bb;
    const int nn = (n0 < 1024) ? n0 : (n0 - 1024);

    for (int kb = 0; kb < 512; kb += 16) {
        {
            const int kg = kb + akq * 4;
            const float4 av = ld4(A + (size_t)(m0 + am) * 512 + kg);
            As[akq * 4 + 0][am] = av.x; As[akq * 4 + 1][am] = av.y;
            As[akq * 4 + 2][am] = av.z; As[akq * 4 + 3][am] = av.w;
        }
        #pragma unroll
        for (int pp = 0; pp < 2; ++pp) {
            const int kg = kb + pp * 8 + bkr;
            *(float4*)&Bs[pp * 8 + bkr][bc4 * 4] = ld4(bp + (size_t)kg * 1024 + nn + bc4 * 4);
        }
        __syncthreads();
        #pragma unroll
        for (int kk = 0; kk < 16; ++kk) {
            const float4 av = *(const float4*)&As[kk][cr * 4];
            const float4 bv = *(const float4*)&Bs[kk][cc * 4];
            const float aa[4] = {av.x, av.y, av.z, av.w};
            const float bbv[4] = {bv.x, bv.y, bv.z, bv.w};
            #pragma unroll
            for (int i = 0; i < 4; ++i)
                #pragma unroll
                for (int j = 0; j < 4; ++j)
                    acc[i][j] = fmaf(aa[i], bbv[j], acc[i][j]);
        }
        __syncthreads();
    }
    #pragma unroll
    for (int i = 0; i < 4; ++i) {
        const int col = nn + cc * 4;
        float4 v = {acc[i][0] + bia[col], acc[i][1] + bia[col + 1],
                    acc[i][2] + bia[col + 2], acc[i][3] + bia[col + 3]};
        st4(xwd + (size_t)(m0 + cr * 4 + i) * 2048 + n0 + cc * 4, v);
    }
}

__global__ __launch_bounds__(256) void dense_kernel(
    const float* __restrict__ hseq, const float* __restrict__ Dk,
    const float* __restrict__ Db, float* __restrict__ out)
{
    __shared__ float dk[8192];
    for (int i = threadIdx.x; i < 8192; i += 256) dk[i] = Dk[i];
    __syncthreads();
    const int f = threadIdx.x & 15;
    const int bt = blockIdx.x * 16 + (threadIdx.x >> 4);
    const float* hs = hseq + (size_t)bt * 512;
    float acc = Db[f];
    #pragma unroll 4
    for (int k = 0; k < 512; k += 4) {
        const float4 hv = ld4(hs + k);
        acc += hv.x * dk[(k + 0) * 16 + f] + hv.y * dk[(k + 1) * 16 + f]
             + hv.z * dk[(k + 2) * 16 + f] + hv.w * dk[(k + 3) * 16 + f];
    }
    out[(size_t)bt * 16 + f] = acc;
}

// ---------------------------------------------------------------------------
extern "C" void kernel_launch(void* const* d_in, const int* in_sizes, int n_in,
                              void* d_out, int out_size, void* d_ws, size_t ws_size,
                              hipStream_t stream)
{
    const float* x    = (const float*)d_in[0];
    const float* encW = (const float*)d_in[1];
    const float* encU = (const float*)d_in[2];
    const float* encB = (const float*)d_in[3];
    const float* dfK  = (const float*)d_in[4];
    const float* dfU  = (const float*)d_in[5];
    const float* dfB  = (const float*)d_in[6];
    const float* dbK  = (const float*)d_in[7];
    const float* dbU  = (const float*)d_in[8];
    const float* dbB  = (const float*)d_in[9];
    const float* dK   = (const float*)d_in[10];
    const float* dB   = (const float*)d_in[11];

    if (ws_size < WS_FLOATS * sizeof(float)) return;

    float* ws   = (float*)d_ws;
    short* bh   = (short*)ws;                    // 1,179,648 shorts (enc only)
    short* bl   = bh + 1179648;                  // 1,179,648 shorts (enc only)
    float* hseq = ws;                            // alias (decoder phase only)
    float* zenc = ws + OFS_ZENC;                 // also zdec (decoder phase)
    float* cenc = ws + OFS_CENC;                 // also cdec (decoder phase)
    float* henc = ws + OFS_HENC;
    float* xwd  = ws + OFS_XWD;

    const int ENC_LDS = 73728;  // 32KB afh + 32KB afl + 8KB red
    hipFuncSetAttribute(reinterpret_cast<const void*>(enc_step_fused),
                        hipFuncAttributeMaxDynamicSharedMemorySize, ENC_LDS);

    // one-time weight fragment packing
    bfrag_prep<<<dim3(36, 64), 64, 0, stream>>>(encW, encU, bh, bl);

    // ---- encoder: 257 fused launches ----
    for (int t = 0; t <= 256; ++t)
        enc_step_fused<<<256, 256, ENC_LDS, stream>>>(x, bh, bl, encB, zenc, cenc, henc, t);

    // ---- decoder ----
    dec_proj<<<dim3(32, 8), 128, 0, stream>>>(henc, dfK, dbK, dfB, dbB, xwd);
    for (int s = 1; s <= 64; ++s)
        dec_step<<<256, 256, 0, stream>>>(dfU, dbU, xwd, zenc, cenc, hseq, s);

    dense_kernel<<<1024, 256, 0, stream>>>(hseq, dK, dB, (float*)d_out);
}